// Round 6
// baseline (196.814 us; speedup 1.0000x reference)
//
#include <hip/hip_runtime.h>
#include <cstdint>
#include <cstddef>

typedef unsigned int u32;
typedef unsigned long long u64;

#define NTOT 122740      // total proposals per batch
#define NQ   30685       // NTOT/4 uint4 per batch
#define NPAIR 61370      // NTOT/2 proposal pairs per batch
#define KTOP 1024        // sorted top-K per batch (expected NMS scan depth ~115)
#define WIN  256         // IoU-matrix window over the sorted list
#define NBIN 512         // histogram bins (cutoff granularity ~±50 is plenty)
#define SCORE_T 0.25f
#define TBITS 0x3E800000u   // bit pattern of 0.25f
#define WS_SCORES 65536     // hist = 32*512*4 = 64 KB at ws offset 0

// level layout: [offset, count) per pyramid level (batch strides in floats: N*6)
// L2: [0,92416) 152x152 s4 | L3: [92416,115520) 76x76 s8
// L4: [115520,121296) 38x38 s16 | L5: [121296,122740) 19x19 s32

// ---------------------------------------------------------------- helpers
__device__ __forceinline__ float sigm(float x) { return 1.0f / (1.0f + expf(-x)); }

// valid scores [0.25,1] -> bins 1..511 (monotone in bits); 0 = invalid
__device__ __forceinline__ int score_bin(u32 bits) {
  return min(NBIN - 1, 1 + (int)((bits - TBITS) >> 15));
}

__device__ float4 decode_box_from_gidx(u32 gidx, int b,
    const float* __restrict__ p2, const float* __restrict__ p3,
    const float* __restrict__ p4, const float* __restrict__ p5)
{
  const float* p; int t, H, W; float stride;
  float aw0, ah0, aw1, ah1, aw2, ah2, aw3, ah3;
  if (gidx < 92416u) {
    p = p2 + (size_t)b * 92416 * 6; t = (int)gidx; H = 152; W = 152; stride = 4.0f;
    aw0=12.f; ah0=16.f; aw1=19.f; ah1=36.f; aw2=40.f; ah2=28.f; aw3=36.f; ah3=75.f;
  } else if (gidx < 115520u) {
    p = p3 + (size_t)b * 23104 * 6; t = (int)(gidx - 92416u); H = 76; W = 76; stride = 8.0f;
    aw0=36.f; ah0=75.f; aw1=76.f; ah1=55.f; aw2=72.f; ah2=146.f; aw3=142.f; ah3=110.f;
  } else if (gidx < 121296u) {
    p = p4 + (size_t)b * 5776 * 6; t = (int)(gidx - 115520u); H = 38; W = 38; stride = 16.0f;
    aw0=72.f; ah0=146.f; aw1=142.f; ah1=110.f; aw2=192.f; ah2=243.f; aw3=459.f; ah3=401.f;
  } else {
    p = p5 + (size_t)b * 1444 * 6; t = (int)(gidx - 121296u); H = 19; W = 19; stride = 32.0f;
    aw0=142.f; ah0=110.f; aw1=192.f; ah1=243.f; aw2=300.f; ah2=300.f; aw3=459.f; ah3=401.f;
  }
  int HW = H * W;
  int a = t / HW;
  int r = t - a * HW;
  int y = r / W;
  int x = r - y * W;
  const float* q = p + (size_t)t * 6;
  float2 t01 = *(const float2*)(q + 0);
  float2 t23 = *(const float2*)(q + 2);
  float cx = (sigm(t01.x) + (float)x) * stride;
  float cy = (sigm(t01.y) + (float)y) * stride;
  float aw = (a == 0) ? aw0 : (a == 1) ? aw1 : (a == 2) ? aw2 : aw3;
  float ah = (a == 0) ? ah0 : (a == 1) ? ah1 : (a == 2) ? ah2 : ah3;
  float bw = expf(t23.x) * aw;
  float bh = expf(t23.y) * ah;
  return make_float4(cx - 0.5f * bw, cy - 0.5f * bh, cx + 0.5f * bw, cy + 0.5f * bh);
}

__device__ __forceinline__ bool iou_gt(float4 A, float4 B) {
  float ltx = fmaxf(A.x, B.x), lty = fmaxf(A.y, B.y);
  float rbx = fminf(A.z, B.z), rby = fminf(A.w, B.w);
  float w = fmaxf(rbx - ltx, 0.0f), h = fmaxf(rby - lty, 0.0f);
  float inter = w * h;
  float a1 = fmaxf(A.z - A.x, 0.0f) * fmaxf(A.w - A.y, 0.0f);
  float a2 = fmaxf(B.z - B.x, 0.0f) * fmaxf(B.w - B.y, 0.0f);
  float iou = inter / (a1 + a2 - inter + 1e-9f);
  return iou > 0.5f;
}

// u64 compare-exchange helpers (bitonic network, ascending overall)
__device__ __forceinline__ u64 shflx_u64(u64 v, int m) {
  u32 lo = (u32)v, hi = (u32)(v >> 32);
  lo = (u32)__shfl_xor((int)lo, m, 64);
  hi = (u32)__shfl_xor((int)hi, m, 64);
  return ((u64)hi << 32) | lo;
}
__device__ __forceinline__ u64 ce_pick(u64 v, u64 p, int i, int jj, int kk) {
  bool up = ((i & kk) == 0);
  bool low = ((i & jj) == 0);
  u64 mn = (v < p) ? v : p;
  u64 mx = (v < p) ? p : v;
  return (low == up) ? mn : mx;
}
__device__ __forceinline__ u64 ce_shfl(u64 v, int i, int jj, int kk) {
  u64 p = shflx_u64(v, jj);
  return ce_pick(v, p, i, jj, kk);
}

// ---------------------------------------------------------------- A: decode + hist
__global__ __launch_bounds__(256)
void decode_score_hist(const float* __restrict__ p2, const float* __restrict__ p3,
                       const float* __restrict__ p4, const float* __restrict__ p5,
                       u32* __restrict__ scores, u32* __restrict__ hist)
{
  __shared__ u32 lhist[NBIN];
  const int tid = threadIdx.x;
  const int b = blockIdx.y;
  for (int i = tid; i < NBIN; i += 256) lhist[i] = 0u;
  __syncthreads();

  uint2* srow = (uint2*)(scores + (size_t)b * NTOT);
  const int pbase = blockIdx.x * 2048;
  #pragma unroll 4
  for (int k = 0; k < 8; ++k) {
    int P = pbase + k * 256 + tid;
    if (P < NPAIR) {
      int t0 = 2 * P;
      const float* p; int l0, LN;
      if (t0 < 92416)       { p = p2; l0 = t0;          LN = 92416; }
      else if (t0 < 115520) { p = p3; l0 = t0 - 92416;  LN = 23104; }
      else if (t0 < 121296) { p = p4; l0 = t0 - 115520; LN = 5776;  }
      else                  { p = p5; l0 = t0 - 121296; LN = 1444;  }
      const float* q = p + ((size_t)b * LN + (size_t)l0) * 6 + 4;
      float4 v1 = *(const float4*)(q);      // conf0, cls0, ., .
      float4 v2 = *(const float4*)(q + 4);  // ., ., conf1, cls1
      float s0 = sigm(v1.x) * sigm(v1.y);
      float s1 = sigm(v2.z) * sigm(v2.w);
      u32 b0 = (s0 >= SCORE_T) ? __float_as_uint(s0) : 0u;
      u32 b1 = (s1 >= SCORE_T) ? __float_as_uint(s1) : 0u;
      srow[P] = make_uint2(b0, b1);
      if (b0) atomicAdd(&lhist[score_bin(b0)], 1u);
      if (b1) atomicAdd(&lhist[score_bin(b1)], 1u);
    }
  }
  __syncthreads();
  u32* gh = hist + (size_t)b * NBIN;
  for (int i = tid; i < NBIN; i += 256) {
    u32 v = lhist[i];
    if (v) atomicAdd(&gh[i], v);
  }
}

// ---------------------------------------------------------------- B: filter+sort+NMS
__global__ __launch_bounds__(1024, 1)
void sort_nms_kernel(const u32* __restrict__ scores, const u32* __restrict__ hist,
                     const float* __restrict__ p2, const float* __restrict__ p3,
                     const float* __restrict__ p4, const float* __restrict__ p5,
                     float* __restrict__ out)
{
  const int b = blockIdx.x;
  const int tid = threadIdx.x;
  const int lane = tid & 63;

  __shared__ u32 shist[NBIN];       // 2 KB
  __shared__ u32 sc[NBIN];          // 2 KB suffix scan
  __shared__ uint2 cand[KTOP];      // 8 KB survivors (unordered)
  __shared__ u64 skey[KTOP];        // 8 KB sort exchange + final sorted keys
  __shared__ float4 sbox[WIN];      // 4 KB window boxes
  __shared__ u64 smat[WIN * 4];     // 8 KB IoU>0.5 bitmatrix (symmetric)
  __shared__ float4 selbox[100];    // slow-path selected boxes
  __shared__ u32 sellist[100];
  __shared__ u32 s_cnt;
  __shared__ int s_B, s_nsel, s_slow;

  // --- 1. load hist, suffix-scan, cutoff B = min{bin : cnt_ge(bin) <= KTOP}
  const u32* gh = hist + (size_t)b * NBIN;
  if (tid < NBIN) { u32 h = gh[tid]; shist[tid] = h; sc[tid] = h; }
  if (tid == 0) { s_cnt = 0u; s_B = NBIN - 1; s_slow = 0; }
  __syncthreads();
  for (int off = 1; off < NBIN; off <<= 1) {
    u32 v = 0;
    if (tid < NBIN && tid + off < NBIN) v = sc[tid + off];
    __syncthreads();
    if (tid < NBIN) sc[tid] += v;
    __syncthreads();
  }
  if (tid < NBIN) {
    if (sc[tid] <= (u32)KTOP && (tid == 0 || sc[tid - 1] > (u32)KTOP))
      s_B = max((int)tid, 1);
  }
  __syncthreads();
  const int B = s_B;

  // --- 2. filter scan: uint4 stream + wave-ballot-aggregated LDS append
  const uint4* sp = (const uint4*)(scores + (size_t)b * NTOT);
  for (int i = tid; i < NQ; i += 1024) {
    uint4 v = sp[i];
    u32 c4[4] = { v.x, v.y, v.z, v.w };
    #pragma unroll
    for (int c = 0; c < 4; ++c) {
      u32 bits = c4[c];
      bool pred = bits && (score_bin(bits) >= B);
      u64 m = __ballot(pred);
      if (m) {
        int leader = (int)__ffsll((unsigned long long)m) - 1;
        u32 base = 0;
        if (lane == leader) base = atomicAdd(&s_cnt, (u32)__popcll(m));
        base = (u32)__shfl((int)base, leader, 64);
        if (pred) {
          u32 pos = base + (u32)__popcll(m & ((1ull << lane) - 1ull));
          if (pos < (u32)KTOP) cand[pos] = make_uint2(bits, (u32)(4 * i + c));
        }
      }
    }
  }
  __syncthreads();
  const int n = min((int)s_cnt, KTOP);

  // --- 3. hybrid bitonic sort (1024 u64): wave-register phases + 10 LDS phases
  u64 v;
  if (tid < n) { uint2 pr = cand[tid]; v = ~(((u64)pr.x << 32) | (u32)(~pr.y)); }
  else v = ~0ull;
  const int i = tid;
  #pragma unroll
  for (int kk = 2; kk <= 64; kk <<= 1)
    #pragma unroll
    for (int jj = kk >> 1; jj > 0; jj >>= 1)
      v = ce_shfl(v, i, jj, kk);
  for (int kk = 128; kk <= KTOP; kk <<= 1) {
    for (int jj = kk >> 1; jj >= 64; jj >>= 1) {
      skey[i] = v; __syncthreads();
      u64 p = skey[i ^ jj]; __syncthreads();
      v = ce_pick(v, p, i, jj, kk);
    }
    #pragma unroll
    for (int jj = 32; jj > 0; jj >>= 1) v = ce_shfl(v, i, jj, kk);
  }
  skey[i] = v;
  __syncthreads();

  const int Wn = min(n, WIN);

  // --- 4. decode window boxes
  if (tid < WIN) {
    sbox[tid] = (tid < Wn) ? decode_box_from_gidx(~(u32)(~skey[tid]), b, p2, p3, p4, p5)
                           : make_float4(0.f, 0.f, 0.f, 0.f);
  }
  __syncthreads();

  // --- 5. IoU bitmatrix (symmetric; diagonal set since iou(x,x)=1>0.5)
  {
    int row = tid >> 2, word = tid & 3;
    u64 bits = 0;
    if (row < Wn) {
      float4 A = sbox[row];
      int j0 = word * 64, je = min(64, Wn - j0);
      for (int j = 0; j < je; ++j)
        if (iou_gt(A, sbox[j0 + j])) bits |= (1ull << j);
    }
    smat[tid] = bits;
  }
  __syncthreads();

  // --- 6. wave-0 register scan: matrix in VGPRs, ballot find-first, no LDS in chain
  if (tid < 64) {
    u64 m0[4], m1[4], m2[4], m3[4];   // m{c}[d] = word d of row (lane+64c)
    #pragma unroll
    for (int d = 0; d < 4; ++d) {
      m0[d] = smat[(lane      ) * 4 + d];
      m1[d] = smat[(lane +  64) * 4 + d];
      m2[d] = smat[(lane + 128) * 4 + d];
      m3[d] = smat[(lane + 192) * 4 + d];
    }
    bool f0 = lane < Wn, f1 = lane + 64 < Wn, f2 = lane + 128 < Wn, f3 = lane + 192 < Wn;
    int sel = 0;
    while (sel < 100) {
      u64 b0 = __ballot(f0), b1 = __ballot(f1), b2 = __ballot(f2), b3 = __ballot(f3);
      int p;
      if (b0)      p = (int)__ffsll((unsigned long long)b0) - 1;
      else if (b1) p = 64 + (int)__ffsll((unsigned long long)b1) - 1;
      else if (b2) p = 128 + (int)__ffsll((unsigned long long)b2) - 1;
      else if (b3) p = 192 + (int)__ffsll((unsigned long long)b3) - 1;
      else break;
      if (lane == 0) sellist[sel] = (u32)p;
      sel++;
      int d = p >> 6, sh = p & 63;
      u64 r0 = (d == 0) ? m0[0] : (d == 1) ? m0[1] : (d == 2) ? m0[2] : m0[3];
      u64 r1 = (d == 0) ? m1[0] : (d == 1) ? m1[1] : (d == 2) ? m1[2] : m1[3];
      u64 r2 = (d == 0) ? m2[0] : (d == 1) ? m2[1] : (d == 2) ? m2[2] : m2[3];
      u64 r3 = (d == 0) ? m3[0] : (d == 1) ? m3[1] : (d == 2) ? m3[2] : m3[3];
      f0 = f0 && !((r0 >> sh) & 1);     // row p suppresses (diag kills p itself)
      f1 = f1 && !((r1 >> sh) & 1);
      f2 = f2 && !((r2 >> sh) & 1);
      f3 = f3 && !((r3 >> sh) & 1);
    }
    if (lane == 0) { s_nsel = sel; s_slow = (sel < 100 && n > WIN) ? 1 : 0; }
  }
  __syncthreads();

  // --- 7. parallel write of selected rows
  const int nsel0 = s_nsel;
  if (tid < nsel0) {
    u32 p = sellist[tid];
    float4 bx = sbox[p];
    u64 kcomp = ~skey[p];
    float scs = __uint_as_float((u32)(kcomp >> 32));
    float* orow = out + (size_t)b * 500 + (size_t)tid * 5;
    orow[0] = bx.x; orow[1] = bx.y; orow[2] = bx.z; orow[3] = bx.w; orow[4] = scs;
  }

  // --- 8. exact slow path beyond the window (statistically never taken)
  if (s_slow) {
    if (tid < nsel0) selbox[tid] = sbox[sellist[tid]];
    __syncthreads();                       // s_slow is block-uniform
    if (tid < 64) {
      int sel = nsel0;
      for (int p = WIN; p < n && sel < 100; ++p) {
        u64 kcomp = ~skey[p];
        float4 box = decode_box_from_gidx(~(u32)kcomp, b, p2, p3, p4, p5);
        bool hit = false;
        if (lane < sel) hit = iou_gt(selbox[lane], box);
        if (lane + 64 < sel) hit = hit || iou_gt(selbox[lane + 64], box);
        u64 anyhit = __ballot(hit);
        if (anyhit == 0ull) {
          if (lane == 0) {
            selbox[sel] = box;
            float scs = __uint_as_float((u32)(kcomp >> 32));
            float* orow = out + (size_t)b * 500 + (size_t)sel * 5;
            orow[0] = box.x; orow[1] = box.y; orow[2] = box.z; orow[3] = box.w; orow[4] = scs;
          }
          sel++;
        }
      }
      if (lane == 0) s_nsel = sel;
    }
  }
  __syncthreads();

  // --- 9. zero-fill remaining rows
  const int nsel = s_nsel;
  for (int k = tid; k < (100 - nsel) * 5; k += 1024)
    out[(size_t)b * 500 + (size_t)nsel * 5 + k] = 0.0f;
}

// ---------------------------------------------------------------- launch
extern "C" void kernel_launch(void* const* d_in, const int* in_sizes, int n_in,
                              void* d_out, int out_size, void* d_ws, size_t ws_size,
                              hipStream_t stream) {
  const float* p2 = (const float*)d_in[0];
  const float* p3 = (const float*)d_in[1];
  const float* p4 = (const float*)d_in[2];
  const float* p5 = (const float*)d_in[3];
  float* out = (float*)d_out;

  u32* hist   = (u32*)d_ws;                               // 32*512*4 = 64 KB
  u32* scores = (u32*)((unsigned char*)d_ws + WS_SCORES); // 32*NTOT*4 = 15.7 MB

  hipMemsetAsync(hist, 0, WS_SCORES, stream);
  decode_score_hist<<<dim3(30, 32), 256, 0, stream>>>(p2, p3, p4, p5, scores, hist);
  sort_nms_kernel<<<32, 1024, 0, stream>>>(scores, hist, p2, p3, p4, p5, out);
}

// Round 7
// 185.394 us; speedup vs baseline: 1.0616x; 1.0616x over previous
//
#include <hip/hip_runtime.h>
#include <cstdint>
#include <cstddef>

typedef unsigned int u32;
typedef unsigned long long u64;

#define NTOT 122740      // total proposals per batch
#define NQ   30685       // NTOT/4 uint4 per batch
#define NPAIR 61370      // NTOT/2 proposal pairs per batch
#define KTOP 1024        // top-K candidates kept per batch (NMS scan depth ~115)
#define WIN  256         // IoU-matrix window over the sorted list
#define NBIN 512
#define SCORE_T 0.25f
#define TBITS 0x3E800000u
#define CSTRIDE 64       // counter padding (u32) -> 256 B apart

// ws layout (bytes):
//   hist:     32*512*4  = 65536   @ 0
//   counters: 32*64*4   = 8192    @ 65536
//   compact:  32*1024*8 = 262144  @ 73728
//   scores:   32*NTOT*4 = 15.7 MB @ 335872
#define WS_COUNTERS 65536
#define WS_COMPACT  73728
#define WS_SCORES   335872

// level layout: [offset,count): L2 [0,92416) 152² s4 | L3 [92416,115520) 76² s8
// L4 [115520,121296) 38² s16 | L5 [121296,122740) 19² s32

// ---------------------------------------------------------------- helpers
__device__ __forceinline__ float sigm(float x) { return 1.0f / (1.0f + expf(-x)); }

// valid scores [0.25,1] -> bins 1..511 (monotone in bits); 0 = invalid
__device__ __forceinline__ int score_bin(u32 bits) {
  return min(NBIN - 1, 1 + (int)((bits - TBITS) >> 15));
}

__device__ float4 decode_box_from_gidx(u32 gidx, int b,
    const float* __restrict__ p2, const float* __restrict__ p3,
    const float* __restrict__ p4, const float* __restrict__ p5)
{
  const float* p; int t, H, W; float stride;
  float aw0, ah0, aw1, ah1, aw2, ah2, aw3, ah3;
  if (gidx < 92416u) {
    p = p2 + (size_t)b * 92416 * 6; t = (int)gidx; H = 152; W = 152; stride = 4.0f;
    aw0=12.f; ah0=16.f; aw1=19.f; ah1=36.f; aw2=40.f; ah2=28.f; aw3=36.f; ah3=75.f;
  } else if (gidx < 115520u) {
    p = p3 + (size_t)b * 23104 * 6; t = (int)(gidx - 92416u); H = 76; W = 76; stride = 8.0f;
    aw0=36.f; ah0=75.f; aw1=76.f; ah1=55.f; aw2=72.f; ah2=146.f; aw3=142.f; ah3=110.f;
  } else if (gidx < 121296u) {
    p = p4 + (size_t)b * 5776 * 6; t = (int)(gidx - 115520u); H = 38; W = 38; stride = 16.0f;
    aw0=72.f; ah0=146.f; aw1=142.f; ah1=110.f; aw2=192.f; ah2=243.f; aw3=459.f; ah3=401.f;
  } else {
    p = p5 + (size_t)b * 1444 * 6; t = (int)(gidx - 121296u); H = 19; W = 19; stride = 32.0f;
    aw0=142.f; ah0=110.f; aw1=192.f; ah1=243.f; aw2=300.f; ah2=300.f; aw3=459.f; ah3=401.f;
  }
  int HW = H * W;
  int a = t / HW;
  int r = t - a * HW;
  int y = r / W;
  int x = r - y * W;
  const float* q = p + (size_t)t * 6;
  float2 t01 = *(const float2*)(q + 0);
  float2 t23 = *(const float2*)(q + 2);
  float cx = (sigm(t01.x) + (float)x) * stride;
  float cy = (sigm(t01.y) + (float)y) * stride;
  float aw = (a == 0) ? aw0 : (a == 1) ? aw1 : (a == 2) ? aw2 : aw3;
  float ah = (a == 0) ? ah0 : (a == 1) ? ah1 : (a == 2) ? ah2 : ah3;
  float bw = expf(t23.x) * aw;
  float bh = expf(t23.y) * ah;
  return make_float4(cx - 0.5f * bw, cy - 0.5f * bh, cx + 0.5f * bw, cy + 0.5f * bh);
}

__device__ __forceinline__ bool iou_gt(float4 A, float4 B) {
  float ltx = fmaxf(A.x, B.x), lty = fmaxf(A.y, B.y);
  float rbx = fminf(A.z, B.z), rby = fminf(A.w, B.w);
  float w = fmaxf(rbx - ltx, 0.0f), h = fmaxf(rby - lty, 0.0f);
  float inter = w * h;
  float a1 = fmaxf(A.z - A.x, 0.0f) * fmaxf(A.w - A.y, 0.0f);
  float a2 = fmaxf(B.z - B.x, 0.0f) * fmaxf(B.w - B.y, 0.0f);
  float iou = inter / (a1 + a2 - inter + 1e-9f);
  return iou > 0.5f;
}

// u64 bitonic compare-exchange helpers
__device__ __forceinline__ u64 shflx_u64(u64 v, int m) {
  u32 lo = (u32)v, hi = (u32)(v >> 32);
  lo = (u32)__shfl_xor((int)lo, m, 64);
  hi = (u32)__shfl_xor((int)hi, m, 64);
  return ((u64)hi << 32) | lo;
}
__device__ __forceinline__ u64 ce_pick(u64 v, u64 p, int i, int jj, int kk) {
  bool up = ((i & kk) == 0);
  bool low = ((i & jj) == 0);
  u64 mn = (v < p) ? v : p;
  u64 mx = (v < p) ? p : v;
  return (low == up) ? mn : mx;
}
__device__ __forceinline__ u64 ce_shfl(u64 v, int i, int jj, int kk) {
  u64 p = shflx_u64(v, jj);
  return ce_pick(v, p, i, jj, kk);
}

// ---------------------------------------------------------------- A: decode + hist
// Dense-staged reads: 3 contiguous float4 per pair go through LDS so every
// VMEM instruction is 64 lanes x 16 B contiguous (1 KiB). 8 chunks of 256 pairs.
__global__ __launch_bounds__(256)
void decode_score_hist(const float* __restrict__ p2, const float* __restrict__ p3,
                       const float* __restrict__ p4, const float* __restrict__ p5,
                       u32* __restrict__ scores, u32* __restrict__ hist)
{
  __shared__ float4 lstage[768];    // 12 KB: 256 pairs * 3 float4
  __shared__ u32 lhist[NBIN];       // 2 KB
  const int tid = threadIdx.x;
  const int b = blockIdx.y;
  for (int i = tid; i < NBIN; i += 256) lhist[i] = 0u;

  uint2* srow = (uint2*)(scores + (size_t)b * NTOT);
  const float* lsf = (const float*)lstage;

  for (int c = 0; c < 8; ++c) {
    const int pb = blockIdx.x * 2048 + c * 256;
    // stage: F = j*256+tid in [0,768); pair P = pb + F/3, component = F%3
    #pragma unroll
    for (int j = 0; j < 3; ++j) {
      int F = j * 256 + tid;
      int Pl = F / 3;                 // compiler magic-mul
      int comp = F - 3 * Pl;
      int P = pb + Pl;
      if (P < NPAIR) {
        int t0 = 2 * P;
        const float* p; int l0, LN;
        if (t0 < 92416)       { p = p2; l0 = t0;          LN = 92416; }
        else if (t0 < 115520) { p = p3; l0 = t0 - 92416;  LN = 23104; }
        else if (t0 < 121296) { p = p4; l0 = t0 - 115520; LN = 5776;  }
        else                  { p = p5; l0 = t0 - 121296; LN = 1444;  }
        lstage[F] = *(const float4*)(p + ((size_t)b * LN + (size_t)l0) * 6 + comp * 4);
      }
    }
    __syncthreads();
    // compute: pair p = pb + tid; conf/cls at float offsets 12t+4,5 and 12t+10,11
    int pr = pb + tid;
    if (pr < NPAIR) {
      float2 cc0 = *(const float2*)(lsf + 12 * tid + 4);
      float2 cc1 = *(const float2*)(lsf + 12 * tid + 10);
      float s0 = sigm(cc0.x) * sigm(cc0.y);
      float s1 = sigm(cc1.x) * sigm(cc1.y);
      u32 b0 = (s0 >= SCORE_T) ? __float_as_uint(s0) : 0u;
      u32 b1 = (s1 >= SCORE_T) ? __float_as_uint(s1) : 0u;
      srow[pr] = make_uint2(b0, b1);
      if (b0) atomicAdd(&lhist[score_bin(b0)], 1u);
      if (b1) atomicAdd(&lhist[score_bin(b1)], 1u);
    }
    __syncthreads();
  }
  u32* gh = hist + (size_t)b * NBIN;
  for (int i = tid; i < NBIN; i += 256) {
    u32 v = lhist[i];
    if (v) atomicAdd(&gh[i], v);
  }
}

// ---------------------------------------------------------------- B1: cutoff + filter
// 15 blocks/batch (480 total). Cheap 512-bin cutoff, 32 KB slice scan,
// rare (~2%) per-survivor LDS atomic, ONE global atomic per block.
__global__ __launch_bounds__(256)
void filter_kernel(const u32* __restrict__ scores, const u32* __restrict__ hist,
                   u32* __restrict__ counters, uint2* __restrict__ compact)
{
  __shared__ u32 shist[NBIN];
  __shared__ u32 scan[256];
  __shared__ uint2 cand[KTOP];
  __shared__ u32 s_cnt, s_base;
  __shared__ int s_B;
  const int tid = threadIdx.x;
  const int b = blockIdx.y;

  const u32* gh = hist + (size_t)b * NBIN;
  shist[tid] = gh[tid];
  shist[tid + 256] = gh[tid + 256];
  if (tid == 0) { s_cnt = 0u; s_B = NBIN - 1; }
  __syncthreads();

  // suffix scan: scan[t] = cnt_ge(2t)
  scan[tid] = shist[2 * tid] + shist[2 * tid + 1];
  __syncthreads();
  for (int off = 1; off < 256; off <<= 1) {
    u32 v = (tid + off < 256) ? scan[tid + off] : 0u;
    __syncthreads();
    scan[tid] += v;
    __syncthreads();
  }
  // cutoff B = min{bin : cnt_ge(bin) <= KTOP}  (deterministic keep-set)
  if (tid == 0 && scan[0] <= (u32)KTOP) s_B = 1;
  {
    u32 nxt = (tid < 255) ? scan[tid + 1] : 0u;
    if (scan[tid] > (u32)KTOP && nxt <= (u32)KTOP) {
      int Bv = 2 * tid + 2;
      if (nxt + shist[2 * tid + 1] <= (u32)KTOP) Bv = 2 * tid + 1;
      s_B = Bv;
    }
  }
  __syncthreads();
  const int B = max(s_B, 1);

  // slice scan (coalesced uint4); survivors are rare -> plain LDS atomic append
  const uint4* sp = (const uint4*)(scores + (size_t)b * NTOT);
  const int i0 = blockIdx.x * 2048;
  const int i1 = min(i0 + 2048, NQ);
  for (int i = i0 + tid; i < i1; i += 256) {
    uint4 v = sp[i];
    u32 c4[4] = { v.x, v.y, v.z, v.w };
    #pragma unroll
    for (int c = 0; c < 4; ++c) {
      u32 bits = c4[c];
      if (bits && score_bin(bits) >= B) {
        u32 pos = atomicAdd(&s_cnt, 1u);
        if (pos < (u32)KTOP) cand[pos] = make_uint2(bits, (u32)(4 * i + c));
      }
    }
  }
  __syncthreads();
  const u32 m = min(s_cnt, (u32)KTOP);
  if (tid == 0) s_base = m ? atomicAdd(&counters[(size_t)b * CSTRIDE], m) : 0u;
  __syncthreads();
  const u32 gbase = s_base;
  uint2* crow = compact + (size_t)b * KTOP;
  for (u32 i = tid; i < m; i += 256) {
    u32 dst = gbase + i;
    if (dst < (u32)KTOP) crow[dst] = cand[i];
  }
}

// ---------------------------------------------------------------- B2: sort + NMS
__global__ __launch_bounds__(1024, 1)
void sort_nms_kernel(const uint2* __restrict__ compact, const u32* __restrict__ counters,
                     const float* __restrict__ p2, const float* __restrict__ p3,
                     const float* __restrict__ p4, const float* __restrict__ p5,
                     float* __restrict__ out)
{
  const int b = blockIdx.x;
  const int tid = threadIdx.x;
  const int lane = tid & 63;

  __shared__ u64 skey[KTOP];        // 8 KB
  __shared__ float4 sbox[WIN];      // 4 KB
  __shared__ u64 smat[WIN * 4];     // 8 KB IoU>0.5 bitmatrix
  __shared__ float4 selbox[100];
  __shared__ u32 sellist[100];
  __shared__ int s_nsel, s_slow;

  const int n = min((int)counters[(size_t)b * CSTRIDE], KTOP);
  const uint2* crow = compact + (size_t)b * KTOP;
  if (tid == 0) s_slow = 0;

  // keys: ~((score_bits<<32)|~gidx)  => ascending sort = score desc, idx asc
  u64 v;
  if (tid < n) { uint2 pr = crow[tid]; v = ~(((u64)pr.x << 32) | (u32)(~pr.y)); }
  else v = ~0ull;

  // hybrid bitonic sort: in-wave shfl phases + 10 cross-wave LDS phases
  const int i = tid;
  #pragma unroll
  for (int kk = 2; kk <= 64; kk <<= 1)
    #pragma unroll
    for (int jj = kk >> 1; jj > 0; jj >>= 1)
      v = ce_shfl(v, i, jj, kk);
  for (int kk = 128; kk <= KTOP; kk <<= 1) {
    for (int jj = kk >> 1; jj >= 64; jj >>= 1) {
      skey[i] = v; __syncthreads();
      u64 p = skey[i ^ jj]; __syncthreads();
      v = ce_pick(v, p, i, jj, kk);
    }
    #pragma unroll
    for (int jj = 32; jj > 0; jj >>= 1) v = ce_shfl(v, i, jj, kk);
  }
  skey[i] = v;
  __syncthreads();

  const int Wn = min(n, WIN);

  // decode window boxes
  if (tid < WIN) {
    sbox[tid] = (tid < Wn) ? decode_box_from_gidx(~(u32)(~skey[tid]), b, p2, p3, p4, p5)
                           : make_float4(0.f, 0.f, 0.f, 0.f);
  }
  __syncthreads();

  // IoU bitmatrix (diagonal set: iou(x,x)=1>0.5)
  {
    int row = tid >> 2, word = tid & 3;
    u64 bits = 0;
    if (row < Wn) {
      float4 A = sbox[row];
      int j0 = word * 64, je = min(64, Wn - j0);
      for (int j = 0; j < je; ++j)
        if (iou_gt(A, sbox[j0 + j])) bits |= (1ull << j);
    }
    smat[tid] = bits;
  }
  __syncthreads();

  // wave-0 register scan: matrix in VGPRs, ballot find-first, no LDS in the chain
  if (tid < 64) {
    u64 m0[4], m1[4], m2[4], m3[4];
    #pragma unroll
    for (int d = 0; d < 4; ++d) {
      m0[d] = smat[(lane      ) * 4 + d];
      m1[d] = smat[(lane +  64) * 4 + d];
      m2[d] = smat[(lane + 128) * 4 + d];
      m3[d] = smat[(lane + 192) * 4 + d];
    }
    bool f0 = lane < Wn, f1 = lane + 64 < Wn, f2 = lane + 128 < Wn, f3 = lane + 192 < Wn;
    int sel = 0;
    while (sel < 100) {
      u64 b0 = __ballot(f0), b1 = __ballot(f1), b2 = __ballot(f2), b3 = __ballot(f3);
      int p;
      if (b0)      p = (int)__ffsll((unsigned long long)b0) - 1;
      else if (b1) p = 64 + (int)__ffsll((unsigned long long)b1) - 1;
      else if (b2) p = 128 + (int)__ffsll((unsigned long long)b2) - 1;
      else if (b3) p = 192 + (int)__ffsll((unsigned long long)b3) - 1;
      else break;
      if (lane == 0) sellist[sel] = (u32)p;
      sel++;
      int d = p >> 6, sh = p & 63;
      u64 r0 = (d == 0) ? m0[0] : (d == 1) ? m0[1] : (d == 2) ? m0[2] : m0[3];
      u64 r1 = (d == 0) ? m1[0] : (d == 1) ? m1[1] : (d == 2) ? m1[2] : m1[3];
      u64 r2 = (d == 0) ? m2[0] : (d == 1) ? m2[1] : (d == 2) ? m2[2] : m2[3];
      u64 r3 = (d == 0) ? m3[0] : (d == 1) ? m3[1] : (d == 2) ? m3[2] : m3[3];
      f0 = f0 && !((r0 >> sh) & 1);
      f1 = f1 && !((r1 >> sh) & 1);
      f2 = f2 && !((r2 >> sh) & 1);
      f3 = f3 && !((r3 >> sh) & 1);
    }
    if (lane == 0) { s_nsel = sel; s_slow = (sel < 100 && n > WIN) ? 1 : 0; }
  }
  __syncthreads();

  // parallel write of selected rows
  const int nsel0 = s_nsel;
  if (tid < nsel0) {
    u32 p = sellist[tid];
    float4 bx = sbox[p];
    float scs = __uint_as_float((u32)((~skey[p]) >> 32));
    float* orow = out + (size_t)b * 500 + (size_t)tid * 5;
    orow[0] = bx.x; orow[1] = bx.y; orow[2] = bx.z; orow[3] = bx.w; orow[4] = scs;
  }

  // exact slow path beyond the window (statistically never taken)
  if (s_slow) {
    if (tid < nsel0) selbox[tid] = sbox[sellist[tid]];
    __syncthreads();
    if (tid < 64) {
      int sel = nsel0;
      for (int p = WIN; p < n && sel < 100; ++p) {
        u64 kcomp = ~skey[p];
        float4 box = decode_box_from_gidx(~(u32)kcomp, b, p2, p3, p4, p5);
        bool hit = false;
        if (lane < sel) hit = iou_gt(selbox[lane], box);
        if (lane + 64 < sel) hit = hit || iou_gt(selbox[lane + 64], box);
        u64 anyhit = __ballot(hit);
        if (anyhit == 0ull) {
          if (lane == 0) {
            selbox[sel] = box;
            float scs = __uint_as_float((u32)(kcomp >> 32));
            float* orow = out + (size_t)b * 500 + (size_t)sel * 5;
            orow[0] = box.x; orow[1] = box.y; orow[2] = box.z; orow[3] = box.w; orow[4] = scs;
          }
          sel++;
        }
      }
      if (lane == 0) s_nsel = sel;
    }
  }
  __syncthreads();

  // zero-fill remaining rows
  const int nsel = s_nsel;
  for (int k = tid; k < (100 - nsel) * 5; k += 1024)
    out[(size_t)b * 500 + (size_t)nsel * 5 + k] = 0.0f;
}

// ---------------------------------------------------------------- launch
extern "C" void kernel_launch(void* const* d_in, const int* in_sizes, int n_in,
                              void* d_out, int out_size, void* d_ws, size_t ws_size,
                              hipStream_t stream) {
  const float* p2 = (const float*)d_in[0];
  const float* p3 = (const float*)d_in[1];
  const float* p4 = (const float*)d_in[2];
  const float* p5 = (const float*)d_in[3];
  float* out = (float*)d_out;

  unsigned char* w = (unsigned char*)d_ws;
  u32*   hist     = (u32*)w;
  u32*   counters = (u32*)(w + WS_COUNTERS);
  uint2* compact  = (uint2*)(w + WS_COMPACT);
  u32*   scores   = (u32*)(w + WS_SCORES);

  hipMemsetAsync(w, 0, WS_COMPACT, stream);   // zero hist + counters
  decode_score_hist<<<dim3(30, 32), 256, 0, stream>>>(p2, p3, p4, p5, scores, hist);
  filter_kernel<<<dim3(15, 32), 256, 0, stream>>>(scores, hist, counters, compact);
  sort_nms_kernel<<<32, 1024, 0, stream>>>(compact, counters, p2, p3, p4, p5, out);
}